// Round 2
// baseline (164.365 us; speedup 1.0000x reference)
//
#include <hip/hip_runtime.h>

#define BTOT 8192
#define TT 512

__device__ __forceinline__ float rcp_f(float x) { return __builtin_amdgcn_rcpf(x); }
__device__ __forceinline__ float bperm(int addr4, float v) {
    return __int_as_float(__builtin_amdgcn_ds_bpermute(addr4, __float_as_int(v)));
}

__global__ __launch_bounds__(64) void lstm_kernel(
    const float* __restrict__ x,
    const float* __restrict__ W_ih,
    const float* __restrict__ W_hh,
    const float* __restrict__ b_ih,
    const float* __restrict__ b_hh,
    const float* __restrict__ fc1_w,
    const float* __restrict__ fc1_b,
    const float* __restrict__ fc2_w,
    const float* __restrict__ fc2_b,
    float* __restrict__ out)
{
    const int lane = threadIdx.x;                 // one wave per block
    const int ll   = (lane < 60) ? lane : 59;     // idle lanes alias lane 59
    const int l    = ll % 20;                     // position within batch group
    const int base = ll - l;                      // group base lane: 0 / 20 / 40
    const int g    = l / 5;                       // gate (0=i,1=f,2=g,3=o)
    const int j    = l % 5;                       // hidden unit (row owner)
    const int b_raw = blockIdx.x * 3 + base / 20;
    const bool write_ok = (lane < 60) && (l == 0) && (b_raw < BTOT);
    const int b = (b_raw < BTOT) ? b_raw : (BTOT - 1);

    // fold activation scaling into weights:
    //  i,f,o: acc = -z      -> sigmoid(z) =      rcp(1+exp(acc))
    //  g    : acc = +2z     -> tanh(z)    = 1 - 2*rcp(1+exp(acc))
    const float sc   = (g == 2) ?  2.0f : -1.0f;
    const float selA = (g == 2) ? -2.0f :  1.0f;
    const float selB = (g == 2) ?  1.0f :  0.0f;

    const int row = g * 5 + j;
    float wihs[5], whhs[5];
    #pragma unroll
    for (int i = 0; i < 5; ++i) {
        wihs[i] = sc * W_ih[row * 5 + i];
        whhs[i] = sc * W_hh[row * 5 + i];
    }
    const float bias_s = sc * (b_ih[row] + b_hh[row]);

    // loop-invariant bpermute byte addresses
    int a_gate[4], a_h[5];
    #pragma unroll
    for (int gg = 0; gg < 4; ++gg) a_gate[gg] = (base + gg * 5 + j) << 2;
    #pragma unroll
    for (int k = 0; k < 5; ++k)    a_h[k]    = (base + g * 5 + k) << 2;

    const float* xb = x + (size_t)b * (TT * 5);

    float hv[5] = {0.f, 0.f, 0.f, 0.f, 0.f};
    float c = 0.f;

    float4 bufA[5], bufB[5];
    #pragma unroll
    for (int i = 0; i < 5; ++i) {
        bufA[i] = *(const float4*)(xb + 0  + 4 * i);   // chunk t=0..3
        bufB[i] = *(const float4*)(xb + 20 + 4 * i);   // chunk t=4..7
    }

    auto process4 = [&](const float4* buf) {
        float xs[20];
        *(float4*)&xs[0]  = buf[0];
        *(float4*)&xs[4]  = buf[1];
        *(float4*)&xs[8]  = buf[2];
        *(float4*)&xs[12] = buf[3];
        *(float4*)&xs[16] = buf[4];

        float gx[4];
        #pragma unroll
        for (int s = 0; s < 4; ++s) {
            float a = bias_s;
            #pragma unroll
            for (int i = 0; i < 5; ++i) a = fmaf(wihs[i], xs[s * 5 + i], a);
            gx[s] = a;
        }

        #pragma unroll
        for (int s = 0; s < 4; ++s) {
            float acc = gx[s];
            #pragma unroll
            for (int k = 0; k < 5; ++k) acc = fmaf(whhs[k], hv[k], acc);
            // own gate's activation
            const float val = fmaf(selA, rcp_f(1.0f + __expf(acc)), selB);
            // round 1: gather all 4 activated gates for unit j (replicated on all lanes)
            const float iv = bperm(a_gate[0], val);
            const float fv = bperm(a_gate[1], val);
            const float gv = bperm(a_gate[2], val);
            const float ov = bperm(a_gate[3], val);
            c = fmaf(fv, c, iv * gv);
            const float tc = fmaf(-2.0f, rcp_f(1.0f + __expf(2.0f * c)), 1.0f);
            const float h  = ov * tc;
            // round 2: broadcast full h-vector for next step
            #pragma unroll
            for (int k = 0; k < 5; ++k) hv[k] = bperm(a_h[k], h);
        }
    };

    for (int t0 = 0; t0 < TT; t0 += 8) {
        process4(bufA);                                // steps t0 .. t0+3
        {   // refill bufA with chunk t0+8 (clamped; redundant tail load harmless)
            const int tld = (t0 + 8 <= TT - 4) ? (t0 + 8) : (TT - 4);
            const float* p = xb + tld * 5;
            #pragma unroll
            for (int i = 0; i < 5; ++i) bufA[i] = *(const float4*)(p + 4 * i);
        }
        process4(bufB);                                // steps t0+4 .. t0+7
        {   // refill bufB with chunk t0+12
            const int tld = (t0 + 12 <= TT - 4) ? (t0 + 12) : (TT - 4);
            const float* p = xb + tld * 5;
            #pragma unroll
            for (int i = 0; i < 5; ++i) bufB[i] = *(const float4*)(p + 4 * i);
        }
    }

    // hv now holds the final hidden state (from last step's round-2 broadcast)
    if (write_ok) {
        float p = fc1_b[0];
        float v = fc2_b[0];
        #pragma unroll
        for (int k = 0; k < 5; ++k) {
            p = fmaf(fc1_w[k], hv[k], p);
            v = fmaf(fc2_w[k], hv[k], v);
        }
        out[b] = p;
        out[BTOT + b] = v;
    }
}

extern "C" void kernel_launch(void* const* d_in, const int* in_sizes, int n_in,
                              void* d_out, int out_size, void* d_ws, size_t ws_size,
                              hipStream_t stream) {
    const float* x     = (const float*)d_in[0];
    const float* W_ih  = (const float*)d_in[1];
    const float* W_hh  = (const float*)d_in[2];
    const float* b_ih  = (const float*)d_in[3];
    const float* b_hh  = (const float*)d_in[4];
    const float* fc1_w = (const float*)d_in[5];
    const float* fc1_b = (const float*)d_in[6];
    const float* fc2_w = (const float*)d_in[7];
    const float* fc2_b = (const float*)d_in[8];
    float* out = (float*)d_out;

    const int blocks = (BTOT + 2) / 3;   // 2731 one-wave blocks, 3 batches each
    lstm_kernel<<<blocks, 64, 0, stream>>>(x, W_ih, W_hh, b_ih, b_hh,
                                           fc1_w, fc1_b, fc2_w, fc2_b, out);
}

// Round 3
// 113.355 us; speedup vs baseline: 1.4500x; 1.4500x over previous
//
#include <hip/hip_runtime.h>

#define BTOT 8192
#define TT 512

__device__ __forceinline__ float rcp_f(float x) { return __builtin_amdgcn_rcpf(x); }
__device__ __forceinline__ float exp2_f(float x) { return __builtin_amdgcn_exp2f(x); }
__device__ __forceinline__ float bperm(int addr4, float v) {
    return __int_as_float(__builtin_amdgcn_ds_bpermute(addr4, __float_as_int(v)));
}
// quad_perm rotations within each 4-lane quad (VALU pipe, no LDS)
__device__ __forceinline__ float dpp_rot1(float v) {
    return __int_as_float(__builtin_amdgcn_mov_dpp(__float_as_int(v), 0x39, 0xf, 0xf, false));
}
__device__ __forceinline__ float dpp_rot2(float v) {
    return __int_as_float(__builtin_amdgcn_mov_dpp(__float_as_int(v), 0x4E, 0xf, 0xf, false));
}
__device__ __forceinline__ float dpp_rot3(float v) {
    return __int_as_float(__builtin_amdgcn_mov_dpp(__float_as_int(v), 0x93, 0xf, 0xf, false));
}

#define LOG2E 1.44269504089f

__global__ __launch_bounds__(64) void lstm_kernel(
    const float* __restrict__ x,
    const float* __restrict__ W_ih,
    const float* __restrict__ W_hh,
    const float* __restrict__ b_ih,
    const float* __restrict__ b_hh,
    const float* __restrict__ fc1_w,
    const float* __restrict__ fc1_b,
    const float* __restrict__ fc2_w,
    const float* __restrict__ fc2_b,
    float* __restrict__ out)
{
    const int lane = threadIdx.x;                 // one wave per block
    const int ll   = (lane < 60) ? lane : 59;     // idle lanes alias lane 59
    const int l    = ll % 20;                     // position within batch group
    const int base = ll - l;                      // group base lane: 0 / 20 / 40
    const int j    = l >> 2;                      // hidden unit (quad index)
    const int g    = l & 3;                       // gate within quad (0=i,1=f,2=g,3=o)
    const int b_raw = blockIdx.x * 3 + base / 20;
    const bool write_ok = (lane < 60) && (l == 0) && (b_raw < BTOT);
    const int b = (b_raw < BTOT) ? b_raw : (BTOT - 1);

    // fold activation scaling (incl. log2e for raw exp2) into weights:
    //  i,f,o: acc = -z*log2e   -> sigmoid(z) =      rcp(1+exp2(acc))
    //  g    : acc = 2z*log2e   -> tanh(z)    = 1 - 2*rcp(1+exp2(acc))
    const float sc   = (g == 2) ? (2.0f * LOG2E) : (-LOG2E);
    const float selA = (g == 2) ? -2.0f :  1.0f;
    const float selB = (g == 2) ?  1.0f :  0.0f;

    const int row = g * 5 + j;                    // PyTorch gate-major row
    float wihs[5], whhs[5];
    #pragma unroll
    for (int i = 0; i < 5; ++i) {
        wihs[i] = sc * W_ih[row * 5 + i];
        whhs[i] = sc * W_hh[row * 5 + i];
    }
    const float bias_s = sc * (b_ih[row] + b_hh[row]);

    // h_k lives on the f-lane (4k+1) of quad k; loop-invariant bpermute addrs
    int a_h[5];
    #pragma unroll
    for (int k = 0; k < 5; ++k) a_h[k] = (base + 4 * k + 1) << 2;

    const float* xb = x + (size_t)b * (TT * 5);

    float hv[5] = {0.f, 0.f, 0.f, 0.f, 0.f};
    float c = 0.f;

    float4 bufA[5], bufB[5];
    #pragma unroll
    for (int i = 0; i < 5; ++i) {
        bufA[i] = *(const float4*)(xb + 0  + 4 * i);   // chunk t=0..3
        bufB[i] = *(const float4*)(xb + 20 + 4 * i);   // chunk t=4..7
    }

    auto process4 = [&](const float4* buf) {
        float xs[20];
        *(float4*)&xs[0]  = buf[0];
        *(float4*)&xs[4]  = buf[1];
        *(float4*)&xs[8]  = buf[2];
        *(float4*)&xs[12] = buf[3];
        *(float4*)&xs[16] = buf[4];

        float gx[4];
        #pragma unroll
        for (int s = 0; s < 4; ++s) {
            float a = bias_s;
            #pragma unroll
            for (int i = 0; i < 5; ++i) a = fmaf(wihs[i], xs[s * 5 + i], a);
            gx[s] = a;
        }

        #pragma unroll
        for (int s = 0; s < 4; ++s) {
            float acc = gx[s];
            #pragma unroll
            for (int k = 0; k < 5; ++k) acc = fmaf(whhs[k], hv[k], acc);
            // own gate activation (raw exp2; scale already folded into weights)
            const float val = fmaf(selA, rcp_f(1.0f + exp2_f(acc)), selB);
            // quad gather via DPP: on f-lane (g==1): r3=i, r1=g, r2=o
            const float r1 = dpp_rot1(val);
            const float r2 = dpp_rot2(val);
            const float r3 = dpp_rot3(val);
            // cell update, redundant on all 4 lanes of the quad (only f-lane meaningful)
            c = fmaf(val, c, r3 * r1);
            const float ec = exp2_f(c * (2.0f * LOG2E));
            const float tc = fmaf(-2.0f, rcp_f(1.0f + ec), 1.0f);
            const float h  = r2 * tc;
            // single LDS round: broadcast h vector from the 5 f-lanes
            #pragma unroll
            for (int k = 0; k < 5; ++k) hv[k] = bperm(a_h[k], h);
        }
    };

    for (int t0 = 0; t0 < TT; t0 += 8) {
        process4(bufA);                                // steps t0 .. t0+3
        {
            const int tld = (t0 + 8 <= TT - 4) ? (t0 + 8) : (TT - 4);
            const float* p = xb + tld * 5;
            #pragma unroll
            for (int i = 0; i < 5; ++i) bufA[i] = *(const float4*)(p + 4 * i);
        }
        process4(bufB);                                // steps t0+4 .. t0+7
        {
            const int tld = (t0 + 12 <= TT - 4) ? (t0 + 12) : (TT - 4);
            const float* p = xb + tld * 5;
            #pragma unroll
            for (int i = 0; i < 5; ++i) bufB[i] = *(const float4*)(p + 4 * i);
        }
    }

    // hv holds the final hidden state (from last step's broadcast)
    if (write_ok) {
        float p = fc1_b[0];
        float v = fc2_b[0];
        #pragma unroll
        for (int k = 0; k < 5; ++k) {
            p = fmaf(fc1_w[k], hv[k], p);
            v = fmaf(fc2_w[k], hv[k], v);
        }
        out[b] = p;
        out[BTOT + b] = v;
    }
}

extern "C" void kernel_launch(void* const* d_in, const int* in_sizes, int n_in,
                              void* d_out, int out_size, void* d_ws, size_t ws_size,
                              hipStream_t stream) {
    const float* x     = (const float*)d_in[0];
    const float* W_ih  = (const float*)d_in[1];
    const float* W_hh  = (const float*)d_in[2];
    const float* b_ih  = (const float*)d_in[3];
    const float* b_hh  = (const float*)d_in[4];
    const float* fc1_w = (const float*)d_in[5];
    const float* fc1_b = (const float*)d_in[6];
    const float* fc2_w = (const float*)d_in[7];
    const float* fc2_b = (const float*)d_in[8];
    float* out = (float*)d_out;

    const int blocks = (BTOT + 2) / 3;   // 2731 one-wave blocks, 3 batches each
    lstm_kernel<<<blocks, 64, 0, stream>>>(x, W_ih, W_hh, b_ih, b_hh,
                                           fc1_w, fc1_b, fc2_w, fc2_b, out);
}